// Round 8
// baseline (352.849 us; speedup 1.0000x reference)
//
#include <hip/hip_runtime.h>
#include <math.h>

#define BSZ  16
#define DIM  768
#define SEQA 1024
#define SEQB 1024

typedef float f32x4 __attribute__((ext_vector_type(4)));
typedef long long llong;

// ---- float <-> order-preserving uint key (atomicMax on floats) ----
__device__ inline unsigned enc_key(float f) {
    unsigned u = __float_as_uint(f);
    return (u & 0x80000000u) ? ~u : (u | 0x80000000u);
}
__device__ inline float dec_key(unsigned k) {
    return (k & 0x80000000u) ? __uint_as_float(k ^ 0x80000000u) : __uint_as_float(~k);
}

// ---- fp8 e4m3 (OCP) / bf16 pack helpers ----
__device__ inline unsigned pk4_fp8(float a, float b, float c, float d) {
    int v = 0;
    v = __builtin_amdgcn_cvt_pk_fp8_f32(a, b, v, false);
    v = __builtin_amdgcn_cvt_pk_fp8_f32(c, d, v, true);
    return (unsigned)v;
}
__device__ inline unsigned char f2fp8(float a) {
    return (unsigned char)(__builtin_amdgcn_cvt_pk_fp8_f32(a, a, 0, false) & 0xFF);
}
__device__ inline unsigned short f2bf(float f) {  // RNE
    unsigned u = __float_as_uint(f);
    return (unsigned short)((u + 0x7FFF + ((u >> 16) & 1)) >> 16);
}
__device__ inline float bf2f(unsigned short h) {
    return __uint_as_float((unsigned)h << 16);
}

// tanh via hardware exp: exact 1.0f in saturation, ~1e-6 error mid-range
__device__ inline float fast_tanh(float x) {
    float ax = fabsf(x);
    float u = __expf(-2.0f * ax);
    float th = __fdividef(1.0f - u, 1.0f + u);
    return copysignf(th, x);
}

// ---- prepass: X[b][DIM][SEQ] f32 -> Xt[b][SEQ][DIM] fp8 + bf16 sidecar ----
__global__ __launch_bounds__(256) void t_cast_AB(const float* __restrict__ A,
                                                 const float* __restrict__ B,
                                                 unsigned char* __restrict__ At,
                                                 unsigned char* __restrict__ Bt,
                                                 unsigned short* __restrict__ At16,
                                                 unsigned short* __restrict__ Bt16,
                                                 int w16) {
    __shared__ float tl[64][68];
    const int z = blockIdx.z;
    const float* X = (z < BSZ) ? A : B;
    unsigned char* Y = (z < BSZ) ? At : Bt;
    unsigned short* Y16 = (z < BSZ) ? At16 : Bt16;
    const int b = z & 15;
    const int d0 = blockIdx.y * 64;
    const int s0 = blockIdx.x * 64;
    const int tid = threadIdx.x;
    const int rr = tid >> 4, c4 = tid & 15;
    const float* Xb = X + ((size_t)b * DIM + d0) * SEQA + s0;
#pragma unroll
    for (int i = 0; i < 4; i++) {
        int row = i * 16 + rr;
        float4 v = *(const float4*)&Xb[(size_t)row * SEQA + c4 * 4];
        *(float4*)&tl[row][c4 * 4] = v;
    }
    __syncthreads();
    const int m = tid & 15, sl = tid >> 4;
    unsigned char* Yb = Y + ((size_t)b * SEQA + s0) * DIM + d0;
#pragma unroll
    for (int i = 0; i < 4; i++) {
        int s = sl + 16 * i;
        unsigned v = pk4_fp8(tl[4 * m + 0][s], tl[4 * m + 1][s], tl[4 * m + 2][s], tl[4 * m + 3][s]);
        *(unsigned*)&Yb[(size_t)s * DIM + 4 * m] = v;
    }
    if (w16) {
        unsigned short* Yc = Y16 + ((size_t)b * SEQA + s0) * DIM + d0;
#pragma unroll
        for (int i = 0; i < 4; i++) {
            int s = sl + 16 * i;
            uint2 w;
            w.x = (unsigned)f2bf(tl[4 * m + 0][s]) | ((unsigned)f2bf(tl[4 * m + 1][s]) << 16);
            w.y = (unsigned)f2bf(tl[4 * m + 2][s]) | ((unsigned)f2bf(tl[4 * m + 3][s]) << 16);
            *(uint2*)&Yc[(size_t)s * DIM + 4 * m] = w;
        }
    }
}

// ---- prepass: U[d][e] f32 -> Ut[e][d] fp8 ; also init max-keys ----
__global__ __launch_bounds__(256) void t_cast_U(const float* __restrict__ U,
                                                unsigned char* __restrict__ Ut,
                                                unsigned* __restrict__ keyA,
                                                unsigned* __restrict__ keyB) {
    __shared__ float tl[64][68];
    const int d0 = blockIdx.y * 64;
    const int e0 = blockIdx.x * 64;
    const int tid = threadIdx.x;
    const int bid = blockIdx.y * gridDim.x + blockIdx.x;
    if (bid < 64) {
        int i = bid * 256 + tid;
        keyA[i] = 0u;
        keyB[i] = 0u;
    }
    const int rr = tid >> 4, c4 = tid & 15;
#pragma unroll
    for (int i = 0; i < 4; i++) {
        int row = i * 16 + rr;
        float4 v = *(const float4*)&U[(size_t)(d0 + row) * DIM + e0 + c4 * 4];
        *(float4*)&tl[row][c4 * 4] = v;
    }
    __syncthreads();
    const int m = tid & 15, sl = tid >> 4;
#pragma unroll
    for (int i = 0; i < 4; i++) {
        int e = sl + 16 * i;
        unsigned v = pk4_fp8(tl[4 * m + 0][e], tl[4 * m + 1][e], tl[4 * m + 2][e], tl[4 * m + 3][e]);
        *(unsigned*)&Ut[(size_t)(e0 + e) * DIM + d0 + 4 * m] = v;
    }
}

// ==== 128-row x 256-B LDS chunk, staged through registers ====
// Global: wave wid covers rows [wid*32, wid*32+32); lane -> (row = lane>>4 (+4p), granule = lane&15)
// -> each 16-lane group reads 256 consecutive bytes (coalesced dwordx4).
__device__ inline void ldchunk(const unsigned char* __restrict__ src, int kb0,
                               uint4* g, int wid, int lane) {
    const int r = wid * 32 + (lane >> 4);
    const int gb = (lane & 15) * 16;
#pragma unroll
    for (int p = 0; p < 8; ++p)
        g[p] = *(const uint4*)(src + (size_t)(r + p * 4) * DIM + kb0 + gb);
}
// LDS write with granule-XOR swizzle: granule gg of row lands at slot gg ^ (row & 15).
__device__ inline void stchunk(const uint4* g, unsigned char* lds, int wid, int lane) {
    const int r = wid * 32 + (lane >> 4);
    const int gg = lane & 15;
#pragma unroll
    for (int p = 0; p < 8; ++p) {
        int row = r + p * 4;
        *(uint4*)(lds + row * 256 + ((gg ^ (row & 15)) << 4)) = g[p];
    }
}
// 8-B fragment read: operand row = rowbase + l15; MFMA k-step kk (0..7) wants bytes
// [kk*32 + quad*8, +8) -> granule g = 2*kk + (quad>>1), half = quad&1. XOR un-swizzle.
__device__ inline llong frag256(const unsigned char* lds, int rowbase, int l15,
                                int quad, int kk) {
    int row = rowbase + l15;
    int g = 2 * kk + (quad >> 1);
    return *(const llong*)(lds + row * 256 + ((g ^ (row & 15)) << 4) + (quad & 1) * 8);
}

// ---- k1: Ct[b][s][e] = sum_d At[b][s][d] * Ut[e][d]  (fp8 MFMA, BK=256, reg-pipeline) ----
// A-side = At (M=s), B-side = Ut (N=e).
__global__ __launch_bounds__(256) void k1_ua(const unsigned char* __restrict__ At,
                                             const unsigned char* __restrict__ Ut,
                                             unsigned char* __restrict__ Ct) {
    __shared__ __align__(16) unsigned char As[128 * 256];
    __shared__ __align__(16) unsigned char Us[128 * 256];
    const int b  = blockIdx.z;
    const int e0 = blockIdx.x * 128;   // x fastest: consecutive blocks reuse the At s-slab
    const int s0 = blockIdx.y * 128;
    const int tid = threadIdx.x;
    const int lane = tid & 63;
    const int wid = tid >> 6;
    const int wr = wid >> 1, wc = wid & 1;
    const int quad = lane >> 4, l15 = lane & 15;

    const unsigned char* Ab = At + (size_t)(b * SEQA + s0) * DIM;
    const unsigned char* Ub = Ut + (size_t)e0 * DIM;

    uint4 ga[8], gu[8];
    ldchunk(Ab, 0, ga, wid, lane);
    ldchunk(Ub, 0, gu, wid, lane);
    stchunk(ga, As, wid, lane);
    stchunk(gu, Us, wid, lane);
    __syncthreads();

    f32x4 acc[4][4] = {};
    for (int it = 0; it < 3; ++it) {
        if (it < 2) {  // prefetch next chunk into regs; lands during ~1.2k cyc of MFMA
            ldchunk(Ab, (it + 1) * 256, ga, wid, lane);
            ldchunk(Ub, (it + 1) * 256, gu, wid, lane);
        }
#pragma unroll
        for (int kk = 0; kk < 8; ++kk) {
            llong av[4], bv[4];
#pragma unroll
            for (int i = 0; i < 4; ++i) av[i] = frag256(As, wr * 64 + 16 * i, l15, quad, kk);
#pragma unroll
            for (int j = 0; j < 4; ++j) bv[j] = frag256(Us, wc * 64 + 16 * j, l15, quad, kk);
#pragma unroll
            for (int i = 0; i < 4; ++i)
#pragma unroll
                for (int j = 0; j < 4; ++j)
                    acc[i][j] = __builtin_amdgcn_mfma_f32_16x16x32_fp8_fp8(av[i], bv[j], acc[i][j], 0, 0, 0);
        }
        if (it < 2) {
            __syncthreads();   // all LDS reads of this chunk done
            stchunk(ga, As, wid, lane);
            stchunk(gu, Us, wid, lane);
            __syncthreads();   // writes visible
        }
    }
    // D: M(s) = wr*64+16i+quad*4+r, N(e) = wc*64+16j+l15 -> byte stores in 16B segments
    unsigned char* Cb = Ct + (size_t)b * SEQA * DIM;
#pragma unroll
    for (int i = 0; i < 4; ++i)
#pragma unroll
        for (int j = 0; j < 4; ++j) {
            int e_g = e0 + wc * 64 + 16 * j + l15;
#pragma unroll
            for (int r = 0; r < 4; ++r) {
                int s_g = s0 + wr * 64 + 16 * i + quad * 4 + r;
                Cb[(size_t)s_g * DIM + e_g] = f2fp8(acc[i][j][r]);
            }
        }
}

// ---- k2: align^T tile = tanh(Bt x Ct) + msk; BK=256 reg-pipeline; fused max -> keys ----
// A-side = Bt (M=t), B-side = Ct (N=s).
__global__ __launch_bounds__(256) void k2_align(const unsigned char* __restrict__ Ct,
                                                const unsigned char* __restrict__ Bt,
                                                const float* __restrict__ msk,
                                                unsigned* __restrict__ keyA,
                                                unsigned* __restrict__ keyB) {
    __shared__ __align__(16) unsigned char Bs[128 * 256];
    __shared__ __align__(16) unsigned char Cs[128 * 256];
    const int b  = blockIdx.z;
    const int t0 = blockIdx.x * 128;   // x fastest: consecutive blocks reuse the Ct s-slab
    const int s0 = blockIdx.y * 128;
    const int tid = threadIdx.x;
    const int lane = tid & 63;
    const int wid = tid >> 6;
    const int wr = wid >> 1, wc = wid & 1;
    const int quad = lane >> 4, l15 = lane & 15;

    const unsigned char* Bb = Bt + (size_t)(b * SEQB + t0) * DIM;
    const unsigned char* Cb = Ct + (size_t)(b * SEQA + s0) * DIM;

    uint4 gb[8], gc[8];
    ldchunk(Bb, 0, gb, wid, lane);
    ldchunk(Cb, 0, gc, wid, lane);
    stchunk(gb, Bs, wid, lane);
    stchunk(gc, Cs, wid, lane);
    __syncthreads();

    f32x4 acc[4][4] = {};
    for (int it = 0; it < 3; ++it) {
        if (it < 2) {
            ldchunk(Bb, (it + 1) * 256, gb, wid, lane);
            ldchunk(Cb, (it + 1) * 256, gc, wid, lane);
        }
#pragma unroll
        for (int kk = 0; kk < 8; ++kk) {
            llong av[4], bv[4];
#pragma unroll
            for (int i = 0; i < 4; ++i) av[i] = frag256(Bs, wr * 64 + 16 * i, l15, quad, kk);
#pragma unroll
            for (int j = 0; j < 4; ++j) bv[j] = frag256(Cs, wc * 64 + 16 * j, l15, quad, kk);
#pragma unroll
            for (int i = 0; i < 4; ++i)
#pragma unroll
                for (int j = 0; j < 4; ++j)
                    acc[i][j] = __builtin_amdgcn_mfma_f32_16x16x32_fp8_fp8(av[i], bv[j], acc[i][j], 0, 0, 0);
        }
        if (it < 2) {
            __syncthreads();
            stchunk(gb, Bs, wid, lane);
            stchunk(gc, Cs, wid, lane);
            __syncthreads();
        }
    }

    // epilogue: tanh + mask.  D: M(t)=wr*64+16i+quad*4+r, N(s)=wc*64+16j+l15
    const float* Mb = msk + (size_t)b * SEQA * SEQB;
#pragma unroll
    for (int i = 0; i < 4; ++i)
#pragma unroll
        for (int j = 0; j < 4; ++j) {
            int s_g = s0 + wc * 64 + 16 * j + l15;
            int t_g = t0 + wr * 64 + 16 * i + quad * 4;
            float4 mv = *(const float4*)&Mb[(size_t)s_g * SEQB + t_g];
            acc[i][j][0] = fast_tanh(acc[i][j][0]) + mv.x;
            acc[i][j][1] = fast_tanh(acc[i][j][1]) + mv.y;
            acc[i][j][2] = fast_tanh(acc[i][j][2]) + mv.z;
            acc[i][j][3] = fast_tanh(acc[i][j][3]) + mv.w;
        }
    // keyA[s]: max over t (in-lane i,r; cross-quad)
#pragma unroll
    for (int j = 0; j < 4; ++j) {
        float m = -INFINITY;
#pragma unroll
        for (int i = 0; i < 4; ++i)
#pragma unroll
            for (int r = 0; r < 4; ++r) m = fmaxf(m, acc[i][j][r]);
        m = fmaxf(m, __shfl_xor(m, 16));
        m = fmaxf(m, __shfl_xor(m, 32));
        if (quad == 0)
            atomicMax(&keyA[b * SEQA + s0 + wc * 64 + 16 * j + l15], enc_key(m));
    }
    // keyB[t]: max over s (in-lane j; cross-l15)
#pragma unroll
    for (int i = 0; i < 4; ++i)
#pragma unroll
        for (int r = 0; r < 4; ++r) {
            float m = fmaxf(fmaxf(acc[i][0][r], acc[i][1][r]), fmaxf(acc[i][2][r], acc[i][3][r]));
            m = fmaxf(m, __shfl_xor(m, 1));
            m = fmaxf(m, __shfl_xor(m, 2));
            m = fmaxf(m, __shfl_xor(m, 4));
            m = fmaxf(m, __shfl_xor(m, 8));
            if (l15 == 0)
                atomicMax(&keyB[b * SEQB + t0 + wr * 64 + 16 * i + quad * 4 + r], enc_key(m));
        }
}

// ---- k3: softmax over per-token maxes ----
__global__ __launch_bounds__(256) void k3_softmax(const unsigned* __restrict__ keyA,
                                                  const unsigned* __restrict__ keyB,
                                                  float* __restrict__ scoreA,
                                                  float* __restrict__ scoreB) {
    const int b = blockIdx.x;
    const bool isA = (blockIdx.y == 0);
    const unsigned* keys = isA ? (keyA + b * SEQA) : (keyB + b * SEQB);
    float* score = isA ? (scoreA + b * SEQA) : (scoreB + b * SEQB);
    __shared__ float sh[4];
    const int tid = threadIdx.x;
    float m[4];
    float mx = -INFINITY;
#pragma unroll
    for (int k = 0; k < 4; k++) {
        m[k] = dec_key(keys[tid + 256 * k]);
        mx = fmaxf(mx, m[k]);
    }
#pragma unroll
    for (int o = 32; o > 0; o >>= 1) mx = fmaxf(mx, __shfl_down(mx, o, 64));
    if ((tid & 63) == 0) sh[tid >> 6] = mx;
    __syncthreads();
    mx = fmaxf(fmaxf(sh[0], sh[1]), fmaxf(sh[2], sh[3]));
    __syncthreads();
    float e[4];
    float sum = 0.f;
#pragma unroll
    for (int k = 0; k < 4; k++) { e[k] = expf(m[k] - mx); sum += e[k]; }
#pragma unroll
    for (int o = 32; o > 0; o >>= 1) sum += __shfl_down(sum, o, 64);
    if ((tid & 63) == 0) sh[tid >> 6] = sum;
    __syncthreads();
    sum = sh[0] + sh[1] + sh[2] + sh[3];
    float inv = 1.0f / sum;
#pragma unroll
    for (int k = 0; k < 4; k++) score[tid + 256 * k] = e[k] * inv;
}

// ---- k4 (bf16 path): out[b,d] += sum_{s in chunk} Xt16[b][s][d] * score[b,s] ----
__global__ __launch_bounds__(256) void k4_bf16(const unsigned short* __restrict__ At16,
                                               const unsigned short* __restrict__ Bt16,
                                               const float* __restrict__ scoreA,
                                               const float* __restrict__ scoreB,
                                               float* __restrict__ out) {
    const int sc = blockIdx.x;
    const int which = blockIdx.y;
    const int b = blockIdx.z;
    const unsigned short* X = which ? Bt16 : At16;
    const float* S = which ? scoreB : scoreA;
    __shared__ float sh[128];
    const int tid = threadIdx.x;
    if (tid < 128) sh[tid] = S[b * SEQA + sc * 128 + tid];
    __syncthreads();
    const unsigned short* Xb = X + ((size_t)b * SEQA + sc * 128) * DIM;
    float a0 = 0.f, a1 = 0.f, a2 = 0.f;
    for (int s = 0; s < 128; ++s) {
        float f = sh[s];
        const unsigned short* row = Xb + (size_t)s * DIM;
        a0 += f * bf2f(row[tid]);
        a1 += f * bf2f(row[tid + 256]);
        a2 += f * bf2f(row[tid + 512]);
    }
    float* o = out + which * (BSZ * DIM) + b * DIM;
    atomicAdd(&o[tid], a0);
    atomicAdd(&o[tid + 256], a1);
    atomicAdd(&o[tid + 512], a2);
}

// ---- k4 (f32 fallback): out[b,d] = sum_s X[b,d,s] * score[b,s] ----
__global__ __launch_bounds__(256) void k4_f32(const float* __restrict__ A,
                                              const float* __restrict__ B,
                                              const float* __restrict__ scoreA,
                                              const float* __restrict__ scoreB,
                                              float* __restrict__ out) {
    const int which = blockIdx.y;
    const int row = blockIdx.x * 4 + (threadIdx.x >> 6);
    const int lane = threadIdx.x & 63;
    const float* X = which ? B : A;
    const float* S = which ? scoreB : scoreA;
    const int b = row / DIM;
    const float4* xr = (const float4*)(X + (size_t)row * SEQA);
    const float4* sr = (const float4*)(S + (size_t)b * SEQA);
    float acc = 0.f;
#pragma unroll
    for (int q = lane; q < SEQA / 4; q += 64) {
        float4 x = xr[q];
        float4 s = sr[q];
        acc += x.x * s.x + x.y * s.y + x.z * s.z + x.w * s.w;
    }
#pragma unroll
    for (int o = 32; o > 0; o >>= 1) acc += __shfl_down(acc, o, 64);
    if (lane == 0) out[which * (BSZ * DIM) + row] = acc;
}

extern "C" void kernel_launch(void* const* d_in, const int* in_sizes, int n_in,
                              void* d_out, int out_size, void* d_ws, size_t ws_size,
                              hipStream_t stream) {
    const float* A   = (const float*)d_in[0];  // (16,768,1024)
    const float* B   = (const float*)d_in[1];  // (16,768,1024)
    const float* msk = (const float*)d_in[2];  // (16,1024,1024)
    const float* U   = (const float*)d_in[3];  // (768,768)
    float* out = (float*)d_out;

    char* ws = (char*)d_ws;
    unsigned char* At = (unsigned char*)ws;                    // 12,582,912
    unsigned char* Bt = (unsigned char*)(ws + 12582912);       // 12,582,912
    unsigned char* Ct = (unsigned char*)(ws + 25165824);       // 12,582,912
    unsigned char* Ut = (unsigned char*)(ws + 37748736);       //    589,824
    unsigned* keyA   = (unsigned*)(ws + 38338560);
    unsigned* keyB   = (unsigned*)(ws + 38404096);
    float*    scoreA = (float*)   (ws + 38469632);
    float*    scoreB = (float*)   (ws + 38535168);
    unsigned short* At16 = (unsigned short*)(ws + 38600704);   // 25,165,824
    unsigned short* Bt16 = (unsigned short*)(ws + 63766528);   // 25,165,824 (end 88,932,352)
    const int w16 = (ws_size >= 88932352ull) ? 1 : 0;          // constant per session -> graph-safe

    t_cast_U<<<dim3(DIM / 64, DIM / 64, 1), 256, 0, stream>>>(U, Ut, keyA, keyB);
    t_cast_AB<<<dim3(SEQA / 64, DIM / 64, 2 * BSZ), 256, 0, stream>>>(A, B, At, Bt, At16, Bt16, w16);
    k1_ua<<<dim3(DIM / 128, SEQA / 128, BSZ), 256, 0, stream>>>(At, Ut, Ct);
    k2_align<<<dim3(SEQB / 128, SEQA / 128, BSZ), 256, 0, stream>>>(Ct, Bt, msk, keyA, keyB);
    k3_softmax<<<dim3(BSZ, 2), 256, 0, stream>>>(keyA, keyB, scoreA, scoreB);
    if (w16) {
        hipMemsetAsync(d_out, 0, (size_t)out_size * sizeof(float), stream);
        k4_bf16<<<dim3(8, 2, BSZ), 256, 0, stream>>>(At16, Bt16, scoreA, scoreB, out);
    } else {
        k4_f32<<<dim3(BSZ * DIM / 4, 2), 256, 0, stream>>>(A, B, scoreA, scoreB, out);
    }
}

// Round 9
// 252.129 us; speedup vs baseline: 1.3995x; 1.3995x over previous
//
#include <hip/hip_runtime.h>
#include <math.h>

#define BSZ  16
#define DIM  768
#define SEQA 1024
#define SEQB 1024

typedef float f32x4 __attribute__((ext_vector_type(4)));
typedef long long llong;

__device__ inline void gload_lds16(const void* g, void* l) {
    __builtin_amdgcn_global_load_lds(
        (const __attribute__((address_space(1))) void*)g,
        (__attribute__((address_space(3))) void*)l, 16, 0, 0);
}

// ---- float <-> order-preserving uint key (atomicMax on floats) ----
__device__ inline unsigned enc_key(float f) {
    unsigned u = __float_as_uint(f);
    return (u & 0x80000000u) ? ~u : (u | 0x80000000u);
}
__device__ inline float dec_key(unsigned k) {
    return (k & 0x80000000u) ? __uint_as_float(k ^ 0x80000000u) : __uint_as_float(~k);
}

// ---- fp8 e4m3 (OCP) / bf16 pack helpers ----
__device__ inline unsigned pk4_fp8(float a, float b, float c, float d) {
    int v = 0;
    v = __builtin_amdgcn_cvt_pk_fp8_f32(a, b, v, false);
    v = __builtin_amdgcn_cvt_pk_fp8_f32(c, d, v, true);
    return (unsigned)v;
}
__device__ inline unsigned char f2fp8(float a) {
    return (unsigned char)(__builtin_amdgcn_cvt_pk_fp8_f32(a, a, 0, false) & 0xFF);
}
__device__ inline unsigned short f2bf(float f) {  // RNE
    unsigned u = __float_as_uint(f);
    return (unsigned short)((u + 0x7FFF + ((u >> 16) & 1)) >> 16);
}
__device__ inline float bf2f(unsigned short h) {
    return __uint_as_float((unsigned)h << 16);
}

// tanh via hardware exp: exact 1.0f in saturation, ~1e-6 error mid-range
__device__ inline float fast_tanh(float x) {
    float ax = fabsf(x);
    float u = __expf(-2.0f * ax);
    float th = __fdividef(1.0f - u, 1.0f + u);
    return copysignf(th, x);
}

// ---- prepass: X[b][DIM][SEQ] f32 -> Xt[b][SEQ][DIM] fp8 + bf16 sidecar ----
__global__ __launch_bounds__(256) void t_cast_AB(const float* __restrict__ A,
                                                 const float* __restrict__ B,
                                                 unsigned char* __restrict__ At,
                                                 unsigned char* __restrict__ Bt,
                                                 unsigned short* __restrict__ At16,
                                                 unsigned short* __restrict__ Bt16,
                                                 int w16) {
    __shared__ float tl[64][68];
    const int z = blockIdx.z;
    const float* X = (z < BSZ) ? A : B;
    unsigned char* Y = (z < BSZ) ? At : Bt;
    unsigned short* Y16 = (z < BSZ) ? At16 : Bt16;
    const int b = z & 15;
    const int d0 = blockIdx.y * 64;
    const int s0 = blockIdx.x * 64;
    const int tid = threadIdx.x;
    const int rr = tid >> 4, c4 = tid & 15;
    const float* Xb = X + ((size_t)b * DIM + d0) * SEQA + s0;
#pragma unroll
    for (int i = 0; i < 4; i++) {
        int row = i * 16 + rr;
        float4 v = *(const float4*)&Xb[(size_t)row * SEQA + c4 * 4];
        *(float4*)&tl[row][c4 * 4] = v;
    }
    __syncthreads();
    const int m = tid & 15, sl = tid >> 4;
    unsigned char* Yb = Y + ((size_t)b * SEQA + s0) * DIM + d0;
#pragma unroll
    for (int i = 0; i < 4; i++) {
        int s = sl + 16 * i;
        unsigned v = pk4_fp8(tl[4 * m + 0][s], tl[4 * m + 1][s], tl[4 * m + 2][s], tl[4 * m + 3][s]);
        *(unsigned*)&Yb[(size_t)s * DIM + 4 * m] = v;
    }
    if (w16) {
        unsigned short* Yc = Y16 + ((size_t)b * SEQA + s0) * DIM + d0;
#pragma unroll
        for (int i = 0; i < 4; i++) {
            int s = sl + 16 * i;
            uint2 w;
            w.x = (unsigned)f2bf(tl[4 * m + 0][s]) | ((unsigned)f2bf(tl[4 * m + 1][s]) << 16);
            w.y = (unsigned)f2bf(tl[4 * m + 2][s]) | ((unsigned)f2bf(tl[4 * m + 3][s]) << 16);
            *(uint2*)&Yc[(size_t)s * DIM + 4 * m] = w;
        }
    }
}

// ---- prepass: U[d][e] f32 -> Ut[e][d] fp8 ; also init max-keys ----
__global__ __launch_bounds__(256) void t_cast_U(const float* __restrict__ U,
                                                unsigned char* __restrict__ Ut,
                                                unsigned* __restrict__ keyA,
                                                unsigned* __restrict__ keyB) {
    __shared__ float tl[64][68];
    const int d0 = blockIdx.y * 64;
    const int e0 = blockIdx.x * 64;
    const int tid = threadIdx.x;
    const int bid = blockIdx.y * gridDim.x + blockIdx.x;
    if (bid < 64) {
        int i = bid * 256 + tid;
        keyA[i] = 0u;
        keyB[i] = 0u;
    }
    const int rr = tid >> 4, c4 = tid & 15;
#pragma unroll
    for (int i = 0; i < 4; i++) {
        int row = i * 16 + rr;
        float4 v = *(const float4*)&U[(size_t)(d0 + row) * DIM + e0 + c4 * 4];
        *(float4*)&tl[row][c4 * 4] = v;
    }
    __syncthreads();
    const int m = tid & 15, sl = tid >> 4;
#pragma unroll
    for (int i = 0; i < 4; i++) {
        int e = sl + 16 * i;
        unsigned v = pk4_fp8(tl[4 * m + 0][e], tl[4 * m + 1][e], tl[4 * m + 2][e], tl[4 * m + 3][e]);
        *(unsigned*)&Ut[(size_t)(e0 + e) * DIM + d0 + 4 * m] = v;
    }
}

// Stage one 128x128-byte tile (rows of `src` pitch DIM) into LDS with granule-XOR
// swizzle. Wave `wid` covers rows [wid*32, wid*32+32).  [round-5 verified]
__device__ inline void stage_tile(const unsigned char* __restrict__ src, int row0,
                                  int kbyte0, unsigned char* lds, int wid, int lane) {
    const int r8 = lane >> 3;              // row within 8-row group
    const int g  = lane & 7;               // dest granule slot
    const int gg = g ^ (r8 & 7);           // source granule (XOR swizzle)
#pragma unroll
    for (int t = 0; t < 4; ++t) {
        int row = row0 + wid * 32 + t * 8 + r8;
        gload_lds16(src + (size_t)row * DIM + kbyte0 + gg * 16,
                    lds + (wid * 32 + t * 8) * 128 + lane * 16);
    }
}

// Read an 8-byte fp8 fragment with matching XOR un-swizzle. [round-5 verified]
__device__ inline llong frag_read(const unsigned char* lds, int rowbase, int l15,
                                  int quad, int h) {
    int gg = 2 * h + (quad >> 1);
    int off = (rowbase + l15) * 128 + ((gg ^ (l15 & 7)) << 4) + (quad & 1) * 8;
    return *(const llong*)(lds + off);
}

// ---- k1: Ct[b][s][e] = sum_d At[b][s][d] * Ut[e][d]  (fp8 MFMA, 128x128, BK=128) ----
// A-side = At (M=s), B-side = Ut (N=e).  [round-5 verified]
__global__ __launch_bounds__(256) void k1_ua(const unsigned char* __restrict__ At,
                                             const unsigned char* __restrict__ Ut,
                                             unsigned char* __restrict__ Ct) {
    __shared__ __align__(16) unsigned char As[128 * 128];
    __shared__ __align__(16) unsigned char Us[128 * 128];
    const int b  = blockIdx.z;
    const int s0 = blockIdx.x * 128;
    const int e0 = blockIdx.y * 128;
    const int tid = threadIdx.x;
    const int lane = tid & 63;
    const int wid = tid >> 6;
    const int wr = wid >> 1, wc = wid & 1;
    const int quad = lane >> 4, l15 = lane & 15;

    const unsigned char* Atb = At + (size_t)b * SEQA * DIM;
    f32x4 acc[4][4] = {};

    for (int d0 = 0; d0 < DIM; d0 += 128) {
        stage_tile(Atb + (size_t)s0 * DIM, 0, d0, As, wid, lane);
        stage_tile(Ut + (size_t)e0 * DIM, 0, d0, Us, wid, lane);
        __syncthreads();
#pragma unroll
        for (int h = 0; h < 4; ++h) {
            llong av[4], bv[4];
#pragma unroll
            for (int i = 0; i < 4; ++i) av[i] = frag_read(As, wr * 64 + 16 * i, l15, quad, h);
#pragma unroll
            for (int j = 0; j < 4; ++j) bv[j] = frag_read(Us, wc * 64 + 16 * j, l15, quad, h);
#pragma unroll
            for (int i = 0; i < 4; ++i)
#pragma unroll
                for (int j = 0; j < 4; ++j)
                    acc[i][j] = __builtin_amdgcn_mfma_f32_16x16x32_fp8_fp8(av[i], bv[j], acc[i][j], 0, 0, 0);
        }
        __syncthreads();
    }
    // D: M(s) = wr*64+16i+quad*4+r, N(e) = wc*64+16j+l15 -> byte stores in 16B segments
    unsigned char* Cb = Ct + (size_t)b * SEQA * DIM;
#pragma unroll
    for (int i = 0; i < 4; ++i)
#pragma unroll
        for (int j = 0; j < 4; ++j) {
            int e_g = e0 + wc * 64 + 16 * j + l15;
#pragma unroll
            for (int r = 0; r < 4; ++r) {
                int s_g = s0 + wr * 64 + 16 * i + quad * 4 + r;
                Cb[(size_t)s_g * DIM + e_g] = f2fp8(acc[i][j][r]);
            }
        }
}

// ---- k2: align^T tile = tanh(Bt x Ct) + msk; fused max -> atomic keys ----
// A-side = Bt (M=t), B-side = Ct (N=s).  [round-5 verified, 59.3 us]
__global__ __launch_bounds__(256, 2) void k2_align(const unsigned char* __restrict__ Ct,
                                                   const unsigned char* __restrict__ Bt,
                                                   const float* __restrict__ msk,
                                                   unsigned* __restrict__ keyA,
                                                   unsigned* __restrict__ keyB) {
    __shared__ __align__(16) unsigned char Cs[128 * 128];
    __shared__ __align__(16) unsigned char Bs[128 * 128];
    const int b  = blockIdx.z;
    const int t0 = blockIdx.x * 128;
    const int s0 = blockIdx.y * 128;
    const int tid = threadIdx.x;
    const int lane = tid & 63;
    const int wid = tid >> 6;
    const int wr = wid >> 1, wc = wid & 1;
    const int quad = lane >> 4, l15 = lane & 15;

    // prefetch mask (HBM) into VGPRs; drained by first K-loop barrier
    const float* Mb = msk + (size_t)b * SEQA * SEQB;
    float4 mv[4][4];
#pragma unroll
    for (int i = 0; i < 4; ++i)
#pragma unroll
        for (int j = 0; j < 4; ++j) {
            int s_g = s0 + wc * 64 + 16 * j + l15;
            int t_g = t0 + wr * 64 + 16 * i + quad * 4;
            mv[i][j] = *(const float4*)&Mb[(size_t)s_g * SEQB + t_g];
        }

    f32x4 acc[4][4] = {};

    for (int e0 = 0; e0 < DIM; e0 += 128) {
        stage_tile(Ct + (size_t)(b * SEQA + s0) * DIM, 0, e0, Cs, wid, lane);
        stage_tile(Bt + (size_t)(b * SEQB + t0) * DIM, 0, e0, Bs, wid, lane);
        __syncthreads();
#pragma unroll
        for (int h = 0; h < 4; ++h) {
            llong av[4], bv[4];
#pragma unroll
            for (int i = 0; i < 4; ++i) av[i] = frag_read(Bs, wr * 64 + 16 * i, l15, quad, h);
#pragma unroll
            for (int j = 0; j < 4; ++j) bv[j] = frag_read(Cs, wc * 64 + 16 * j, l15, quad, h);
#pragma unroll
            for (int i = 0; i < 4; ++i)
#pragma unroll
                for (int j = 0; j < 4; ++j)
                    acc[i][j] = __builtin_amdgcn_mfma_f32_16x16x32_fp8_fp8(av[i], bv[j], acc[i][j], 0, 0, 0);
        }
        __syncthreads();
    }

    // epilogue: tanh + prefetched mask.  D: M(t)=wr*64+16i+quad*4+r, N(s)=wc*64+16j+l15
#pragma unroll
    for (int i = 0; i < 4; ++i)
#pragma unroll
        for (int j = 0; j < 4; ++j) {
            acc[i][j][0] = fast_tanh(acc[i][j][0]) + mv[i][j].x;
            acc[i][j][1] = fast_tanh(acc[i][j][1]) + mv[i][j].y;
            acc[i][j][2] = fast_tanh(acc[i][j][2]) + mv[i][j].z;
            acc[i][j][3] = fast_tanh(acc[i][j][3]) + mv[i][j].w;
        }
    // keyA[s]: max over t (in-lane i,r; cross-quad)
#pragma unroll
    for (int j = 0; j < 4; ++j) {
        float m = -INFINITY;
#pragma unroll
        for (int i = 0; i < 4; ++i)
#pragma unroll
            for (int r = 0; r < 4; ++r) m = fmaxf(m, acc[i][j][r]);
        m = fmaxf(m, __shfl_xor(m, 16));
        m = fmaxf(m, __shfl_xor(m, 32));
        if (quad == 0)
            atomicMax(&keyA[b * SEQA + s0 + wc * 64 + 16 * j + l15], enc_key(m));
    }
    // keyB[t]: max over s (in-lane j; cross-l15)
#pragma unroll
    for (int i = 0; i < 4; ++i)
#pragma unroll
        for (int r = 0; r < 4; ++r) {
            float m = fmaxf(fmaxf(acc[i][0][r], acc[i][1][r]), fmaxf(acc[i][2][r], acc[i][3][r]));
            m = fmaxf(m, __shfl_xor(m, 1));
            m = fmaxf(m, __shfl_xor(m, 2));
            m = fmaxf(m, __shfl_xor(m, 4));
            m = fmaxf(m, __shfl_xor(m, 8));
            if (l15 == 0)
                atomicMax(&keyB[b * SEQB + t0 + wr * 64 + 16 * i + quad * 4 + r], enc_key(m));
        }
}

// ---- k3: softmax over per-token maxes ----
__global__ __launch_bounds__(256) void k3_softmax(const unsigned* __restrict__ keyA,
                                                  const unsigned* __restrict__ keyB,
                                                  float* __restrict__ scoreA,
                                                  float* __restrict__ scoreB) {
    const int b = blockIdx.x;
    const bool isA = (blockIdx.y == 0);
    const unsigned* keys = isA ? (keyA + b * SEQA) : (keyB + b * SEQB);
    float* score = isA ? (scoreA + b * SEQA) : (scoreB + b * SEQB);
    __shared__ float sh[4];
    const int tid = threadIdx.x;
    float m[4];
    float mx = -INFINITY;
#pragma unroll
    for (int k = 0; k < 4; k++) {
        m[k] = dec_key(keys[tid + 256 * k]);
        mx = fmaxf(mx, m[k]);
    }
#pragma unroll
    for (int o = 32; o > 0; o >>= 1) mx = fmaxf(mx, __shfl_down(mx, o, 64));
    if ((tid & 63) == 0) sh[tid >> 6] = mx;
    __syncthreads();
    mx = fmaxf(fmaxf(sh[0], sh[1]), fmaxf(sh[2], sh[3]));
    __syncthreads();
    float e[4];
    float sum = 0.f;
#pragma unroll
    for (int k = 0; k < 4; k++) { e[k] = expf(m[k] - mx); sum += e[k]; }
#pragma unroll
    for (int o = 32; o > 0; o >>= 1) sum += __shfl_down(sum, o, 64);
    if ((tid & 63) == 0) sh[tid >> 6] = sum;
    __syncthreads();
    sum = sh[0] + sh[1] + sh[2] + sh[3];
    float inv = 1.0f / sum;
#pragma unroll
    for (int k = 0; k < 4; k++) score[tid + 256 * k] = e[k] * inv;
}

// ---- k4 (bf16 path): out[b,d] += sum_{s in chunk} Xt16[b][s][d] * score[b,s] ----
__global__ __launch_bounds__(256) void k4_bf16(const unsigned short* __restrict__ At16,
                                               const unsigned short* __restrict__ Bt16,
                                               const float* __restrict__ scoreA,
                                               const float* __restrict__ scoreB,
                                               float* __restrict__ out) {
    const int sc = blockIdx.x;
    const int which = blockIdx.y;
    const int b = blockIdx.z;
    const unsigned short* X = which ? Bt16 : At16;
    const float* S = which ? scoreB : scoreA;
    __shared__ float sh[128];
    const int tid = threadIdx.x;
    if (tid < 128) sh[tid] = S[b * SEQA + sc * 128 + tid];
    __syncthreads();
    const unsigned short* Xb = X + ((size_t)b * SEQA + sc * 128) * DIM;
    float a0 = 0.f, a1 = 0.f, a2 = 0.f;
    for (int s = 0; s < 128; ++s) {
        float f = sh[s];
        const unsigned short* row = Xb + (size_t)s * DIM;
        a0 += f * bf2f(row[tid]);
        a1 += f * bf2f(row[tid + 256]);
        a2 += f * bf2f(row[tid + 512]);
    }
    float* o = out + which * (BSZ * DIM) + b * DIM;
    atomicAdd(&o[tid], a0);
    atomicAdd(&o[tid + 256], a1);
    atomicAdd(&o[tid + 512], a2);
}

// ---- k4 (f32 fallback): out[b,d] = sum_s X[b,d,s] * score[b,s] ----
__global__ __launch_bounds__(256) void k4_f32(const float* __restrict__ A,
                                              const float* __restrict__ B,
                                              const float* __restrict__ scoreA,
                                              const float* __restrict__ scoreB,
                                              float* __restrict__ out) {
    const int which = blockIdx.y;
    const int row = blockIdx.x * 4 + (threadIdx.x >> 6);
    const int lane = threadIdx.x & 63;
    const float* X = which ? B : A;
    const float* S = which ? scoreB : scoreA;
    const int b = row / DIM;
    const float4* xr = (const float4*)(X + (size_t)row * SEQA);
    const float4* sr = (const float4*)(S + (size_t)b * SEQA);
    float acc = 0.f;
#pragma unroll
    for (int q = lane; q < SEQA / 4; q += 64) {
        float4 x = xr[q];
        float4 s = sr[q];
        acc += x.x * s.x + x.y * s.y + x.z * s.z + x.w * s.w;
    }
#pragma unroll
    for (int o = 32; o > 0; o >>= 1) acc += __shfl_down(acc, o, 64);
    if (lane == 0) out[which * (BSZ * DIM) + row] = acc;
}

extern "C" void kernel_launch(void* const* d_in, const int* in_sizes, int n_in,
                              void* d_out, int out_size, void* d_ws, size_t ws_size,
                              hipStream_t stream) {
    const float* A   = (const float*)d_in[0];  // (16,768,1024)
    const float* B   = (const float*)d_in[1];  // (16,768,1024)
    const float* msk = (const float*)d_in[2];  // (16,1024,1024)
    const float* U   = (const float*)d_in[3];  // (768,768)
    float* out = (float*)d_out;

    char* ws = (char*)d_ws;
    unsigned char* At = (unsigned char*)ws;                    // 12,582,912
    unsigned char* Bt = (unsigned char*)(ws + 12582912);       // 12,582,912
    unsigned char* Ct = (unsigned char*)(ws + 25165824);       // 12,582,912
    unsigned char* Ut = (unsigned char*)(ws + 37748736);       //    589,824
    unsigned* keyA   = (unsigned*)(ws + 38338560);
    unsigned* keyB   = (unsigned*)(ws + 38404096);
    float*    scoreA = (float*)   (ws + 38469632);
    float*    scoreB = (float*)   (ws + 38535168);
    unsigned short* At16 = (unsigned short*)(ws + 38600704);   // 25,165,824
    unsigned short* Bt16 = (unsigned short*)(ws + 63766528);   // 25,165,824 (end 88,932,352)
    const int w16 = (ws_size >= 88932352ull) ? 1 : 0;          // constant per session -> graph-safe

    t_cast_U<<<dim3(DIM / 64, DIM / 64, 1), 256, 0, stream>>>(U, Ut, keyA, keyB);
    t_cast_AB<<<dim3(SEQA / 64, DIM / 64, 2 * BSZ), 256, 0, stream>>>(A, B, At, Bt, At16, Bt16, w16);
    k1_ua<<<dim3(SEQA / 128, DIM / 128, BSZ), 256, 0, stream>>>(At, Ut, Ct);
    k2_align<<<dim3(SEQB / 128, SEQA / 128, BSZ), 256, 0, stream>>>(Ct, Bt, msk, keyA, keyB);
    k3_softmax<<<dim3(BSZ, 2), 256, 0, stream>>>(keyA, keyB, scoreA, scoreB);
    if (w16) {
        hipMemsetAsync(d_out, 0, (size_t)out_size * sizeof(float), stream);
        k4_bf16<<<dim3(8, 2, BSZ), 256, 0, stream>>>(At16, Bt16, scoreA, scoreB, out);
    } else {
        k4_f32<<<dim3(BSZ * DIM / 4, 2), 256, 0, stream>>>(A, B, scoreA, scoreB, out);
    }
}